// Round 2
// baseline (602.551 us; speedup 1.0000x reference)
//
#include <hip/hip_runtime.h>
#include <math.h>

// Problem constants (match reference)
#define Bc 4
#define Cc 16
#define Hc 128
#define Gc 64

// Tile: 4x4x16 voxels per 256-thread block
#define TZ 4
#define TY 4
#define TXX 16
#define HZ (TZ + 2)
#define HY (TY + 2)
#define HXX (TXX + 2)
#define HALO_PER_C (HZ * HY * HXX)   // 648 floats per channel
#define CH_PER_PASS 8

__global__ __launch_bounds__(256, 2) void nca_fused(
    const float* __restrict__ x,
    const float* __restrict__ W1,
    const float* __restrict__ b1,
    const float* __restrict__ W2,
    const float* __restrict__ stoch,
    float* __restrict__ out)
{
    // LDS: weights (guaranteed-cheap broadcast reads) + 8-channel x halo
    __shared__ float w1s[Hc * 64];                 // 32768 B
    __shared__ float w2ts[Hc * Cc];                // 8192 B (transposed: [h][k])
    __shared__ float b1s[Hc];                      // 512 B
    __shared__ float xs[CH_PER_PASS * HALO_PER_C]; // 20736 B  -> total 62208 B

    const int tid = threadIdx.x;

    // Block -> (b, zt, yt, xt)
    int bid = blockIdx.x;
    const int xt = bid % (Gc / TXX); bid /= (Gc / TXX);
    const int yt = bid % (Gc / TY); bid /= (Gc / TY);
    const int zt = bid % (Gc / TZ); bid /= (Gc / TZ);
    const int b  = bid;

    const int z0 = zt * TZ, y0 = yt * TY, x0 = xt * TXX;

    // ---- Stage weights into LDS (once per block) ----
    {
        const float4* W1v = (const float4*)W1;
        float4* w1sv = (float4*)w1s;
#pragma unroll
        for (int i = 0; i < (Hc * 64 / 4) / 256; ++i)
            w1sv[tid + i * 256] = W1v[tid + i * 256];
        if (tid < Hc) b1s[tid] = b1[tid];
        // W2 (Cc x Hc) -> transposed LDS [h][k]; reads coalesced, LDS write
        // conflicts are a one-time cost (8 instr/thread).
#pragma unroll
        for (int i = 0; i < (Cc * Hc) / 256; ++i) {
            const int idx = tid + i * 256;
            const int k = idx >> 7;        // idx / Hc
            const int h = idx & (Hc - 1);  // idx % Hc
            w2ts[h * Cc + k] = W2[idx];
        }
    }

    const int tx = tid % TXX;
    const int ty = (tid / TXX) % TY;
    const int tz = tid / (TXX * TY);

    // ---- Perception in two 8-channel passes ----
    float p[64];
    float pooled = -1e30f;

#pragma unroll
    for (int pass = 0; pass < 2; ++pass) {
        __syncthreads();  // weights staged (pass 0) / xs no longer read (pass 1)
        for (int idx = tid; idx < CH_PER_PASS * HALO_PER_C; idx += 256) {
            int hx = idx % HXX;
            int t  = idx / HXX;
            int hy = t % HY; t /= HY;
            int hz = t % HZ;
            int cc = t / HZ;
            const int c = pass * CH_PER_PASS + cc;
            int gz = z0 + hz - 1, gy = y0 + hy - 1, gx = x0 + hx - 1;
            float v = 0.0f;
            if ((unsigned)gz < (unsigned)Gc && (unsigned)gy < (unsigned)Gc &&
                (unsigned)gx < (unsigned)Gc) {
                v = x[(((b * Cc + c) * Gc + gz) * Gc + gy) * Gc + gx];
            }
            xs[idx] = v;
        }
        __syncthreads();

#pragma unroll
        for (int cc = 0; cc < CH_PER_PASS; ++cc) {
            const int g = pass * CH_PER_PASS + cc;  // global channel
            const float* xc = &xs[cc * HALO_PER_C];
            float S[3][3], D[3][3];
            float center = 0.0f;
#pragma unroll
            for (int dz = 0; dz < 3; ++dz) {
#pragma unroll
                for (int dy = 0; dy < 3; ++dy) {
                    const int base = (tz + dz) * (HY * HXX) + (ty + dy) * HXX + tx;
                    const float a  = xc[base + 0];
                    const float m  = xc[base + 1];
                    const float c2 = xc[base + 2];
                    S[dz][dy] = a + 2.0f * m + c2;   // smooth along x
                    D[dz][dy] = c2 - a;              // diff along x
                    if (dz == 1 && dy == 1) center = m;
                    if (g == 3) pooled = fmaxf(pooled, fmaxf(fmaxf(a, m), c2));
                }
            }
            // sobel_x: s_z s_y d_x
            const float sx = (D[0][0] + 2.0f * D[0][1] + D[0][2])
                     + 2.0f * (D[1][0] + 2.0f * D[1][1] + D[1][2])
                     +        (D[2][0] + 2.0f * D[2][1] + D[2][2]);
            // sobel_y: s_z d_y s_x
            const float sy = (S[0][2] - S[0][0])
                     + 2.0f * (S[1][2] - S[1][0])
                     +        (S[2][2] - S[2][0]);
            // sobel_z: d_z s_y s_x
            const float sz = (S[2][0] + 2.0f * S[2][1] + S[2][2])
                           - (S[0][0] + 2.0f * S[0][1] + S[0][2]);
            p[4 * g + 0] = center;
            p[4 * g + 1] = sx;
            p[4 * g + 2] = sy;
            p[4 * g + 3] = sz;
        }
    }

    // Zero-pad is equivalent to -inf pad for the alive test since thresh > 0
    const float alive = (pooled > 0.1f) ? 1.0f : 0.0f;

    // ---- MLP: dx = W2 * relu(W1 * p + b1), weights broadcast from LDS ----
    float dxv[16];
#pragma unroll
    for (int k = 0; k < 16; ++k) dxv[k] = 0.0f;

#pragma unroll 1
    for (int o = 0; o < Hc; o += 8) {
        float acc[8];
#pragma unroll
        for (int i = 0; i < 8; ++i) acc[i] = b1s[o + i];
#pragma unroll
        for (int i = 0; i < 8; ++i) {
            const float4* w4 = (const float4*)&w1s[(o + i) * 64];
#pragma unroll
            for (int c4 = 0; c4 < 16; ++c4) {
                const float4 w = w4[c4];
                acc[i] = fmaf(w.x, p[4 * c4 + 0], acc[i]);
                acc[i] = fmaf(w.y, p[4 * c4 + 1], acc[i]);
                acc[i] = fmaf(w.z, p[4 * c4 + 2], acc[i]);
                acc[i] = fmaf(w.w, p[4 * c4 + 3], acc[i]);
            }
        }
#pragma unroll
        for (int i = 0; i < 8; ++i) {
            const float h = fmaxf(acc[i], 0.0f);
            const float4* w2 = (const float4*)&w2ts[(o + i) * Cc];
#pragma unroll
            for (int k4 = 0; k4 < 4; ++k4) {
                const float4 w = w2[k4];
                dxv[4 * k4 + 0] = fmaf(w.x, h, dxv[4 * k4 + 0]);
                dxv[4 * k4 + 1] = fmaf(w.y, h, dxv[4 * k4 + 1]);
                dxv[4 * k4 + 2] = fmaf(w.z, h, dxv[4 * k4 + 2]);
                dxv[4 * k4 + 3] = fmaf(w.w, h, dxv[4 * k4 + 3]);
            }
        }
    }

    // ---- Epilogue: stochastic update, alive mask, angle wrap ----
    const int gz = z0 + tz, gy = y0 + ty, gx = x0 + tx;
    const int vox = ((b * Gc + gz) * Gc + gy) * Gc + gx;
    const float sm = (stoch[vox] <= 0.5f) ? 1.0f : 0.0f;

    const float TWO_PI_F = 6.2831854820251464844f;  // float(2*pi)

#pragma unroll
    for (int k = 0; k < 16; ++k) {
        const float xn = p[4 * k] + dxv[k] * sm;
        float res;
        if (k < 15) {
            res = xn * alive;
        } else {
            res = fmodf(xn, TWO_PI_F);
            if (res < 0.0f) res += TWO_PI_F;
        }
        out[(((b * Cc + k) * Gc + gz) * Gc + gy) * Gc + gx] = res;
    }
}

extern "C" void kernel_launch(void* const* d_in, const int* in_sizes, int n_in,
                              void* d_out, int out_size, void* d_ws, size_t ws_size,
                              hipStream_t stream) {
    const float* x     = (const float*)d_in[0];
    // d_in[1] = percep_kernel: fixed sobel structure, hardcoded in kernel
    const float* W1    = (const float*)d_in[2];
    const float* b1    = (const float*)d_in[3];
    const float* W2    = (const float*)d_in[4];
    const float* stoch = (const float*)d_in[5];
    float* out = (float*)d_out;

    const int nblocks = Bc * (Gc / TZ) * (Gc / TY) * (Gc / TXX);  // 4096
    nca_fused<<<nblocks, 256, 0, stream>>>(x, W1, b1, W2, stoch, out);
}